// Round 8
// baseline (152.627 us; speedup 1.0000x reference)
//
#include <hip/hip_runtime.h>
#include <hip/hip_bf16.h>

#define BATCH 4
#define CH 256
#define CRD 32
#define NN 4096

typedef __bf16 bf16x8 __attribute__((ext_vector_type(8)));
typedef float floatx4 __attribute__((ext_vector_type(4)));
typedef float floatx16 __attribute__((ext_vector_type(16)));
typedef unsigned short ushort4v __attribute__((ext_vector_type(4)));
typedef unsigned short ushort8v __attribute__((ext_vector_type(8)));
typedef unsigned int uint2v __attribute__((ext_vector_type(2)));
typedef unsigned int uint4v __attribute__((ext_vector_type(4)));

// Native bf16 convert: lowers to v_cvt_pk_bf16_f32 (RNE).
static __device__ __forceinline__ unsigned short f2bf(float f) {
    __bf16 h = (__bf16)f;
    return __builtin_bit_cast(unsigned short, h);
}
static __device__ __forceinline__ float bf2f(unsigned short h) {
    return __uint_as_float((unsigned int)h << 16);
}

// ---------------------------------------------------------------------------
// Fragment layout conventions (32x32x16 bf16 MFMA), verified R2-R8:
//   A[m][k]: lane l holds m = l&31, k = (l>>5)*8 + j
//   B[k][n]: lane l holds n = l&31, k = (l>>5)*8 + j
//   D      : lane l holds col = l&31, row = (r&3) + 8*(r>>2) + 4*(l>>5)
// Frag-major storage: addr = (tile*64 + (d32&31) + 32*((d16>>3)&1))*8 + (d16&7)
//
// REGISTER-BUDGET RULE (paid R3, R8, R10): never demand occupancy beyond
// ~20% headroom over the estimated VGPR need.
// LEDGER (R5): V traffic = (#q-tile blocks) x (V rows scanned) — invariant
// to key-split; only Q-TILE SIZE reduces it.
// LEDGER (R6): TLP matters across kernels; CU residency interacts.
// LEDGER (R7): full fusion (ks=1) = 256 blocks = 1/CU -> attn +12us. The
// fused epilogue needs all channels+keys block-local -> can't have both
// fusion and >=2 blocks/CU at q-tile 64. REVERTED to R6 structure.
// LEDGER (R7b): kernel boundary ~10us (R6->R7 rest delta with one fewer
// kernel). Boundaries are a real cost: fewer kernels, same structure.
//
// R16 (this round): DELETE wconv kernel; attn/out byte-frozen at R6.
//   * qkv inlines its A-frags straight from Wq/Wk/Wv f32: lane l, kblk ->
//     8 contiguous f32 at W[row][kblk*16 + h*8] -> 2x dwordx4 + cvt_pk.
//     Weights 328KB, L2-resident after first blocks. What deleted.
//     Wq softmax*log2e scale applied post-GEMM to wave-0 acc (linear).
//   * WobF produced by 4 side-blocks in qkv (grid 129x4, blockIdx.x==128,
//     uniform early-return branch -> no barrier hazard). out unchanged.
// ---------------------------------------------------------------------------

#define QSCALE (0.17677669529663687f * 1.4426950408889634f)

// Exchange rg-quad packs across the h halves (lanes +-32) -> one full 16B
// lane-contiguous store. Layout in memory bit-identical to scalar path.
static __device__ __forceinline__ uint4v hmerge(
    const ushort4v& xp, const ushort4v& yp, int h)
{
    uint2v xd = __builtin_bit_cast(uint2v, xp);
    uint2v yd = __builtin_bit_cast(uint2v, yp);
    unsigned int px0 = (unsigned int)__shfl_xor((int)xd[0], 32);
    unsigned int px1 = (unsigned int)__shfl_xor((int)xd[1], 32);
    unsigned int py0 = (unsigned int)__shfl_xor((int)yd[0], 32);
    unsigned int py1 = (unsigned int)__shfl_xor((int)yd[1], 32);
    uint4v st;
    st[0] = h ? py0 : xd[0];
    st[1] = h ? py1 : xd[1];
    st[2] = h ? yd[0] : px0;
    st[3] = h ? yd[1] : px1;
    return st;
}

// ---------------------------------------------------------------------------
// K1: QKV GEMM + weight prep fused. grid (129 x 4): blocks x<128 do the
// GEMM for n-tile x (10 waves, wave w = one output chain mb=w); block
// x==128 converts WobF rows [64b, 64b+64) (early uniform return).
// A-frags built inline from f32 weights (2x dwordx4 + cvt per kblk).
// V exits via XOR-swizzled xf-LDS bounce -> dense b128 vh writes.
// ---------------------------------------------------------------------------
__global__ __launch_bounds__(640, 4) void qkv_kernel(
    const float* __restrict__ x,
    const float* __restrict__ Wq, const float* __restrict__ Wk,
    const float* __restrict__ Wv, const float* __restrict__ Wo,
    unsigned short* __restrict__ qh, unsigned short* __restrict__ kh,
    unsigned short* __restrict__ vh, unsigned short* __restrict__ WobF)
{
    __shared__ __align__(16) unsigned short xf[16 * 512];  // 16 KB; reused for V

    const int t = threadIdx.x;
    const int nt = blockIdx.x, b = blockIdx.y;

    // ---- side-block: WobF conversion for rows [64b, 64b+64) ----
    if (nt == 128) {
        for (int i = t; i < 16384; i += 640) {
            int r = i >> 8;                 // 0..63
            int c = i & 255;
            int o = 64 * b + r;
            size_t dst = ((size_t)((o >> 5) * 16 + (c >> 4)) * 64
                          + (o & 31) + 32 * ((c >> 3) & 1)) * 8 + (c & 7);
            WobF[dst] = f2bf(Wo[o * 256 + c]);
        }
        return;
    }

    const int w = t >> 6;          // 0..9
    const int l = t & 63;
    const int l31 = l & 31;
    const int h = l >> 5;
    const int n0 = nt * 32;

    // ---- stage: threads 0..511; thread (n = t&31, cq = t>>5 in [0,16)) ----
    if (t < 512) {
        const float* xb = x + (size_t)(b * CH) * NN + n0;
        const int n = t & 31;
        const int cq = t >> 5;           // 0..15
        #pragma unroll
        for (int p = 0; p < 4; ++p) {
            int c = p * 64 + cq * 4;
            float v0 = xb[(size_t)(c + 0) * NN + n];
            float v1 = xb[(size_t)(c + 1) * NN + n];
            float v2 = xb[(size_t)(c + 2) * NN + n];
            float v3 = xb[(size_t)(c + 3) * NN + n];
            ushort4v u4;
            u4[0] = f2bf(v0); u4[1] = f2bf(v1); u4[2] = f2bf(v2); u4[3] = f2bf(v3);
            int addr = ((4 * p + (cq >> 2)) * 64 + n + 32 * ((cq >> 1) & 1)) * 8
                       + 4 * (cq & 1);
            *(ushort4v*)&xf[addr] = u4;
        }
    }
    __syncthreads();

    // per-wave weight row pointer: wave w -> chain mb=w
    //   w0: Wq row l31 | w1: Wk row l31 | w>=2: Wv row (w-2)*32 + l31
    const float* wrow;
    if (w == 0)      wrow = Wq + (size_t)l31 * 256;
    else if (w == 1) wrow = Wk + (size_t)l31 * 256;
    else             wrow = Wv + ((size_t)(w - 2) * 32 + l31) * 256;
    wrow += h * 8;   // lane's k-offset within each kblk

    floatx16 acc;
    #pragma unroll
    for (int i = 0; i < 16; ++i) acc[i] = 0.f;

    for (int kblk = 0; kblk < 16; ++kblk) {
        bf16x8 bf = *(const bf16x8*)&xf[kblk * 512 + l * 8];
        floatx4 wa = *(const floatx4*)(wrow + kblk * 16);
        floatx4 wb = *(const floatx4*)(wrow + kblk * 16 + 4);
        ushort8v au;
        au[0] = f2bf(wa[0]); au[1] = f2bf(wa[1]);
        au[2] = f2bf(wa[2]); au[3] = f2bf(wa[3]);
        au[4] = f2bf(wb[0]); au[5] = f2bf(wb[1]);
        au[6] = f2bf(wb[2]); au[7] = f2bf(wb[3]);
        bf16x8 af = *(bf16x8*)&au;
        acc = __builtin_amdgcn_mfma_f32_32x32x16_bf16(af, bf, acc, 0, 0, 0);
    }

    // wave 0: fold softmax scale * log2e into q (linear; was pre-scaled Wq)
    if (w == 0) {
        #pragma unroll
        for (int i = 0; i < 16; ++i) acc[i] *= QSCALE;
    }

    // q/k: full-line b128 stores via h-exchange (layout bit-identical)
    auto store_qk = [&](unsigned short* dst, const floatx16& a) {
        size_t base = (size_t)(b * 128 + nt) * 1024;
        #pragma unroll
        for (int sb = 0; sb < 2; ++sb) {
            ushort4v xp, yp;
            #pragma unroll
            for (int i = 0; i < 4; ++i) {
                xp[i] = f2bf(a[8 * sb + i]);
                yp[i] = f2bf(a[8 * sb + 4 + i]);
            }
            uint4v st = hmerge(xp, yp, h);
            *(uint4v*)(dst + base + (size_t)sb * 512 + (size_t)l * 8) = st;
        }
    };

    if (w == 0)      store_qk(qh, acc);
    else if (w == 1) store_qk(kh, acc);

    __syncthreads();   // all xf (GEMM B-frag) reads done; reuse xf for V

    // v staged to LDS in vh-chunk layout with XOR bank swizzle.
    if (w >= 2) {
        const int cblk = w - 2;
        const int chunk = cblk * 2 + (l31 >> 4);
        const int hib = (l31 >> 3) & 1;
        #pragma unroll
        for (int r = 0; r < 16; ++r) {
            int rowo = (r & 3) + 8 * (r >> 2) + 4 * h;
            int unit = chunk * 64 + hib * 32 + rowo;
            int pu = unit ^ ((unit >> 5) & 7);
            xf[pu * 8 + (l31 & 7)] = f2bf(acc[r]);
        }
    }

    __syncthreads();

    // copy LDS -> vh: 16 chunks x 1KB, each contiguous in global. Dense b128.
    if (t < 512) {
        #pragma unroll
        for (int p = 0; p < 2; ++p) {
            int Lu = p * 512 + t;             // logical unit 0..1023
            int pu = Lu ^ ((Lu >> 5) & 7);
            uint4v d = *(const uint4v*)&xf[pu * 8];
            int chunk = Lu >> 6;
            int cblk = chunk >> 1, sub = chunk & 1;
            size_t dst = (((size_t)b * 8 + cblk) * 256 + nt * 2 + sub) * 512
                         + (size_t)(Lu & 63) * 8;
            *(uint4v*)(vh + dst) = d;
        }
    }
}

// ---------------------------------------------------------------------------
// K2: flash attention (FROZEN at R6/R14). Q-tile 64, 8 waves, key-split 2.
// grid (64 qt-pairs, 2 ks, 4 b) = 512 blocks; XCD remap combo = lin&7.
// Fixed-shift softmax P = 2^(S-12); one barrier/iter; 16 its.
// ---------------------------------------------------------------------------
#define SM_M0 12.0f

__global__ __launch_bounds__(512, 4) void attn_kernel(
    const unsigned short* __restrict__ qh, const unsigned short* __restrict__ kh,
    const unsigned short* __restrict__ vh, unsigned short* __restrict__ Opart,
    float* __restrict__ ml)
{
    __shared__ unsigned short p_lds[2 * 16 * 64 * 8];   // 32 KB, double-buffered
    __shared__ float psum_s[8][32];

    const int t = threadIdx.x;
    const int w = t >> 6;          // 0..7
    const int l = t & 63;
    const int l31 = l & 31;
    const int h = l >> 5;
    const int wk = w & 3;          // key sub-slice
    const int hq = w >> 2;         // q-half for S phase

    const int lin = blockIdx.x + ((int)blockIdx.y << 6) + ((int)blockIdx.z << 7);
    const int combo = lin & 7;
    const int gp = lin >> 3;                          // 0..63 qt-pair
    const int ks = combo & 1;
    const int b  = combo >> 1;
    const int g0 = 2 * gp, g1 = 2 * gp + 1;

    const unsigned short* qB = qh + (size_t)(b * 128 + (hq ? g1 : g0)) * 1024;
    const unsigned short* kB = kh + (size_t)b * 128 * 1024;
    const unsigned short* vB = vh + (size_t)b * 8 * 256 * 512;

    bf16x8 qf0 = *(const bf16x8*)(qB + l * 8);
    bf16x8 qf1 = *(const bf16x8*)(qB + 512 + l * 8);

    bf16x8 kf0 = *(const bf16x8*)(kB + (size_t)(ks * 64 + wk) * 1024 + l * 8);
    bf16x8 kf1 = *(const bf16x8*)(kB + (size_t)(ks * 64 + wk) * 1024 + 512 + l * 8);

    float l_loc = 0.f;
    floatx16 acc_a, acc_b;        // cblk w, q-halves a/b
    #pragma unroll
    for (int i = 0; i < 16; ++i) { acc_a[i] = 0.f; acc_b[i] = 0.f; }

    for (int it = 0; it < 16; ++it) {
        const int pbase = (it & 1) << 13;            // 8192 ushorts per buffer

        floatx16 sacc;
        #pragma unroll
        for (int i = 0; i < 16; ++i) sacc[i] = 0.f;
        __builtin_amdgcn_s_setprio(1);
        sacc = __builtin_amdgcn_mfma_f32_32x32x16_bf16(kf0, qf0, sacc, 0, 0, 0);
        sacc = __builtin_amdgcn_mfma_f32_32x32x16_bf16(kf1, qf1, sacc, 0, 0, 0);
        __builtin_amdgcn_s_setprio(0);

        float pv[16];
        #pragma unroll
        for (int r = 0; r < 16; ++r) pv[r] = __builtin_exp2f(sacc[r] - SM_M0);
        float s0 = (pv[0] + pv[1]) + (pv[2] + pv[3]);
        float s1 = (pv[4] + pv[5]) + (pv[6] + pv[7]);
        float s2 = (pv[8] + pv[9]) + (pv[10] + pv[11]);
        float s3 = (pv[12] + pv[13]) + (pv[14] + pv[15]);
        l_loc += (s0 + s1) + (s2 + s3);
        #pragma unroll
        for (int rg = 0; rg < 4; ++rg) {
            ushort4v pk;
            #pragma unroll
            for (int i = 0; i < 4; ++i) pk[i] = f2bf(pv[rg * 4 + i]);
            int idx = pbase
                    + ((hq * 8 + 2 * wk + (rg >> 1)) * 64
                       + l31 + 32 * (rg & 1)) * 8 + 4 * h;
            *(ushort4v*)&p_lds[idx] = pk;
        }
        if (it < 15) {
            const unsigned short* kn = kB + (size_t)(ks * 64 + (it + 1) * 4 + wk) * 1024;
            kf0 = *(const bf16x8*)(kn + l * 8);
            kf1 = *(const bf16x8*)(kn + 512 + l * 8);
        }
        const unsigned short* v0b = vB + ((size_t)w * 256 + (ks * 16 + it) * 8) * 512;
        bf16x8 va0 = *(const bf16x8*)(v0b + 0 * 512 + l * 8);
        bf16x8 va1 = *(const bf16x8*)(v0b + 1 * 512 + l * 8);
        bf16x8 va2 = *(const bf16x8*)(v0b + 2 * 512 + l * 8);
        bf16x8 va3 = *(const bf16x8*)(v0b + 3 * 512 + l * 8);
        bf16x8 va4 = *(const bf16x8*)(v0b + 4 * 512 + l * 8);
        bf16x8 va5 = *(const bf16x8*)(v0b + 5 * 512 + l * 8);
        bf16x8 va6 = *(const bf16x8*)(v0b + 6 * 512 + l * 8);
        bf16x8 va7 = *(const bf16x8*)(v0b + 7 * 512 + l * 8);

        __syncthreads();   // p_lds[pbase] visible; prev-buffer reads long done

        bf16x8 pa = *(const bf16x8*)&p_lds[pbase + l * 8];
        bf16x8 pb = *(const bf16x8*)&p_lds[pbase + 4096 + l * 8];
        #pragma unroll
        for (int s = 0; s < 8; ++s) {
            bf16x8 vcur = (s == 0) ? va0 : (s == 1) ? va1 : (s == 2) ? va2
                        : (s == 3) ? va3 : (s == 4) ? va4 : (s == 5) ? va5
                        : (s == 6) ? va6 : va7;
            bf16x8 pa_n, pb_n;
            if (s < 7) {
                pa_n = *(const bf16x8*)&p_lds[pbase + ((s + 1) * 64 + l) * 8];
                pb_n = *(const bf16x8*)&p_lds[pbase + 4096 + ((s + 1) * 64 + l) * 8];
            }
            __builtin_amdgcn_s_setprio(1);
            acc_a = __builtin_amdgcn_mfma_f32_32x32x16_bf16(vcur, pa, acc_a, 0, 0, 0);
            acc_b = __builtin_amdgcn_mfma_f32_32x32x16_bf16(vcur, pb, acc_b, 0, 0, 0);
            __builtin_amdgcn_s_setprio(0);
            pa = pa_n; pb = pb_n;
        }
    }

    float lt = l_loc + __shfl_xor(l_loc, 32);
    if (h == 0) psum_s[w][l31] = lt;
    __syncthreads();

    if (w == 0 && h == 0) {
        float l_run = (psum_s[0][l31] + psum_s[1][l31])
                    + (psum_s[2][l31] + psum_s[3][l31]);
        ml[((size_t)(b * 128 + g0) * 2 + ks) * 32 + l31] = l_run;
    }
    if (w == 4 && h == 0) {
        float l_run = (psum_s[4][l31] + psum_s[5][l31])
                    + (psum_s[6][l31] + psum_s[7][l31]);
        ml[((size_t)(b * 128 + g1) * 2 + ks) * 32 + l31] = l_run;
    }

    unsigned short* opa = Opart + ((size_t)((b * 128 + g0) * 2 + ks)) * 8192;
    unsigned short* opb = Opart + ((size_t)((b * 128 + g1) * 2 + ks)) * 8192;
    #pragma unroll
    for (int ct = 0; ct < 2; ++ct) {
        const floatx16& a = ct ? acc_b : acc_a;
        unsigned short* op = ct ? opb : opa;
        #pragma unroll
        for (int sb = 0; sb < 2; ++sb) {
            ushort4v xp, yp;
            #pragma unroll
            for (int i = 0; i < 4; ++i) {
                xp[i] = f2bf(a[8 * sb + i]);
                yp[i] = f2bf(a[8 * sb + 4 + i]);
            }
            uint4v st = hmerge(xp, yp, h);
            int sP = 2 * w + sb;
            *(uint4v*)(op + ((size_t)sP * 64 + l) * 8) = st;
        }
    }
}

// ---------------------------------------------------------------------------
// K3: Wo GEMM (FROZEN at R6). m-split grid (128 qt, 2 mhalf, 4 b), 4 waves;
// wave owns m-tile mt = mhalf*4 + w with TWO exact MFMA chains (one per
// key-split partial), then (a0+a1) * 1/(l0+l1) post-GEMM + gamma*out + x.
// ---------------------------------------------------------------------------
__global__ __launch_bounds__(256, 4) void out_kernel(
    const unsigned short* __restrict__ Opart, const float* __restrict__ ml,
    const unsigned short* __restrict__ WobF, const float* __restrict__ x,
    const float* __restrict__ gamma, float* __restrict__ out)
{
    const int t = threadIdx.x;
    const int w = t >> 6;
    const int l = t & 63;
    const int l31 = l & 31;
    const int h = l >> 5;
    const int qt = blockIdx.x, mhalf = blockIdx.y, b = blockIdx.z;
    const int mt = mhalf * 4 + w;

    const size_t slot2 = (size_t)(b * 128 + qt) * 2;
    float l0 = ml[(slot2 + 0) * 32 + l31];
    float l1 = ml[(slot2 + 1) * 32 + l31];
    float rL = 1.0f / (l0 + l1);     // per-lane: D-layout col = l31 = query

    const unsigned short* o0 = Opart + (slot2 + 0) * 8192;
    const unsigned short* o1 = Opart + (slot2 + 1) * 8192;

    floatx16 a0, a1;
    #pragma unroll
    for (int i = 0; i < 16; ++i) { a0[i] = 0.f; a1[i] = 0.f; }

    for (int s = 0; s < 16; ++s) {
        bf16x8 f0 = *(const bf16x8*)(o0 + (s * 64 + l) * 8);
        bf16x8 f1 = *(const bf16x8*)(o1 + (s * 64 + l) * 8);
        bf16x8 af = *(const bf16x8*)(WobF + ((size_t)(mt * 16 + s) * 64 + l) * 8);
        a0 = __builtin_amdgcn_mfma_f32_32x32x16_bf16(af, f0, a0, 0, 0, 0);
        a1 = __builtin_amdgcn_mfma_f32_32x32x16_bf16(af, f1, a1, 0, 0, 0);
    }

    const float gm = gamma[0];
    #pragma unroll
    for (int r = 0; r < 16; ++r) {
        float v = (a0[r] + a1[r]) * rL;
        int o = mt * 32 + (r & 3) + 8 * (r >> 2) + 4 * h;
        int n = qt * 32 + l31;
        size_t oi = ((size_t)(b * 256 + o)) * NN + n;
        out[oi] = gm * v + x[oi];
    }
}

// ---------------------------------------------------------------------------
extern "C" void kernel_launch(void* const* d_in, const int* in_sizes, int n_in,
                              void* d_out, int out_size, void* d_ws, size_t ws_size,
                              hipStream_t stream)
{
    const float* x     = (const float*)d_in[0];
    const float* Wq    = (const float*)d_in[1];
    const float* Wk    = (const float*)d_in[2];
    const float* Wv    = (const float*)d_in[3];
    const float* Wo    = (const float*)d_in[4];
    const float* gamma = (const float*)d_in[5];
    float* out = (float*)d_out;

    char* wsb = (char*)d_ws;
    unsigned short* qh    = (unsigned short*)(wsb);                          // 1 MB
    unsigned short* kh    = (unsigned short*)(wsb + (1u << 20));             // 1 MB
    unsigned short* vh    = (unsigned short*)(wsb + (2u << 20));             // 8 MB
    unsigned short* WobF  = (unsigned short*)(wsb + (10u << 20) + (256u << 10)); // 128 KB
    unsigned short* Opart = (unsigned short*)(wsb + (11u << 20));            // 16.8 MB (ks=2)
    float*          ml    = (float*)         (wsb + (45u << 20));            // 128 KB

    dim3 g1(129, BATCH);
    qkv_kernel<<<g1, 640, 0, stream>>>(x, Wq, Wk, Wv, Wo, qh, kh, vh, WobF);

    dim3 g2(64, 2, BATCH);
    attn_kernel<<<g2, 512, 0, stream>>>(qh, kh, vh, Opart, ml);

    dim3 g3(128, 2, BATCH);
    out_kernel<<<g3, 256, 0, stream>>>(Opart, ml, WobF, x, gamma, out);
}

// Round 9
// 136.221 us; speedup vs baseline: 1.1204x; 1.1204x over previous
//
#include <hip/hip_runtime.h>
#include <hip/hip_bf16.h>

#define BATCH 4
#define CH 256
#define CRD 32
#define NN 4096

typedef __bf16 bf16x8 __attribute__((ext_vector_type(8)));
typedef float floatx4 __attribute__((ext_vector_type(4)));
typedef float floatx16 __attribute__((ext_vector_type(16)));
typedef unsigned short ushort4v __attribute__((ext_vector_type(4)));
typedef unsigned short ushort8v __attribute__((ext_vector_type(8)));
typedef unsigned int uint2v __attribute__((ext_vector_type(2)));
typedef unsigned int uint4v __attribute__((ext_vector_type(4)));

// Native bf16 convert: lowers to v_cvt_pk_bf16_f32 (RNE).
static __device__ __forceinline__ unsigned short f2bf(float f) {
    __bf16 h = (__bf16)f;
    return __builtin_bit_cast(unsigned short, h);
}
static __device__ __forceinline__ float bf2f(unsigned short h) {
    return __uint_as_float((unsigned int)h << 16);
}

// ---------------------------------------------------------------------------
// Fragment layout conventions (32x32x16 bf16 MFMA), verified R2-R8:
//   A[m][k]: lane l holds m = l&31, k = (l>>5)*8 + j
//   B[k][n]: lane l holds n = l&31, k = (l>>5)*8 + j
//   D      : lane l holds col = l&31, row = (r&3) + 8*(r>>2) + 4*(l>>5)
// Frag-major storage: addr = (tile*64 + (d32&31) + 32*((d16>>3)&1))*8 + (d16&7)
//
// REGISTER-BUDGET RULE (paid R3, R8, R10): never demand occupancy beyond
// ~20% headroom over the estimated VGPR need.
// LEDGER (R5): V traffic = (#q-tile blocks) x (V rows scanned) — invariant
// to key-split; only Q-TILE SIZE reduces it.
// LEDGER (R6): TLP matters across kernels; CU residency interacts.
// LEDGER (R7): full fusion (ks=1) = 1 block/CU -> attn +12us. Can't have
// fusion AND >=2 blocks/CU at q-tile 64. R6 structure is the keeper.
// LEDGER (R8): inlining weight prep into qkv = 128x redundant conversion +
// scattered f32 loads in the hot loop = +16us. Precompute shared transforms
// (wconv) when reuse is high; kernel-boundary cost (~10us) < that.
//
// R17 (this round): wconv/qkv/out restored EXACTLY to R6. attn restructured:
//   PIPELINE ROTATION. Old: S(it)->softmax(it)->store->barrier->PV(it):
//   all 8 waves in the same phase per barrier region -> MFMA pipe idle
//   during softmax, VALU idle during PV (MfmaUtil 33%, VALU 42%, never
//   co-issued). New body: {S(it+1) MFMA; V(it) loads; softmax(it+1) VALU;
//   P(it+1)->other buf; K(it+2) loads; PV(it); barrier} — softmax VALU and
//   V-load latency now interleave with MFMA issue inside one region.
//   Still 1 barrier/it, double-buffered p_lds, same math/rounding.
// ---------------------------------------------------------------------------

// ---------------------------------------------------------------------------
// K0: weight prep. mb0 = Wq pre-scaled by softmax_scale * log2(e).
// ---------------------------------------------------------------------------
__global__ __launch_bounds__(256) void wconv_kernel(
    const float* __restrict__ Wq, const float* __restrict__ Wk,
    const float* __restrict__ Wv, const float* __restrict__ Wo,
    unsigned short* __restrict__ What, unsigned short* __restrict__ WobF)
{
    const int o = blockIdx.x;
    const int t = threadIdx.x;   // input channel c
    float scale = 1.0f;
    const float* src;
    if (o < 32)      { src = Wq + o * 256;
                       scale = 0.17677669529663687f * 1.4426950408889634f; }
    else if (o < 64) { src = Wk + (o - 32) * 256; }
    else             { src = Wv + (o - 64) * 256; }
    const int mb = o >> 5;
    const size_t idx = ((size_t)(mb * 16 + (t >> 4)) * 64
                        + (o & 31) + 32 * ((t >> 3) & 1)) * 8 + (t & 7);
    What[idx] = f2bf(src[t] * scale);
    if (o < 256) {
        const size_t i2 = ((size_t)((o >> 5) * 16 + (t >> 4)) * 64
                           + (o & 31) + 32 * ((t >> 3) & 1)) * 8 + (t & 7);
        WobF[i2] = f2bf(Wo[o * 256 + t]);
    }
}

// Exchange rg-quad packs across the h halves (lanes +-32) -> one full 16B
// lane-contiguous store. Layout in memory bit-identical to scalar path.
static __device__ __forceinline__ uint4v hmerge(
    const ushort4v& xp, const ushort4v& yp, int h)
{
    uint2v xd = __builtin_bit_cast(uint2v, xp);
    uint2v yd = __builtin_bit_cast(uint2v, yp);
    unsigned int px0 = (unsigned int)__shfl_xor((int)xd[0], 32);
    unsigned int px1 = (unsigned int)__shfl_xor((int)xd[1], 32);
    unsigned int py0 = (unsigned int)__shfl_xor((int)yd[0], 32);
    unsigned int py1 = (unsigned int)__shfl_xor((int)yd[1], 32);
    uint4v st;
    st[0] = h ? py0 : xd[0];
    st[1] = h ? py1 : xd[1];
    st[2] = h ? yd[0] : px0;
    st[3] = h ? yd[1] : px1;
    return st;
}

// ---------------------------------------------------------------------------
// K1: QKV GEMM (R6 exact). grid (128 n-tiles, 4 b), block 640 (10 waves).
// Wave w owns ONE output chain mb=w: w0->q, w1->k, w2..9->v cblk (w-2).
// V exits via XOR-swizzled xf-LDS bounce -> dense b128 vh writes.
// ---------------------------------------------------------------------------
__global__ __launch_bounds__(640, 4) void qkv_kernel(
    const float* __restrict__ x, const unsigned short* __restrict__ What,
    unsigned short* __restrict__ qh, unsigned short* __restrict__ kh,
    unsigned short* __restrict__ vh)
{
    __shared__ __align__(16) unsigned short xf[16 * 512];  // 16 KB; reused for V

    const int t = threadIdx.x;
    const int w = t >> 6;          // 0..9
    const int l = t & 63;
    const int l31 = l & 31;
    const int h = l >> 5;
    const int nt = blockIdx.x, b = blockIdx.y;
    const int n0 = nt * 32;

    if (t < 512) {
        const float* xb = x + (size_t)(b * CH) * NN + n0;
        const int n = t & 31;
        const int cq = t >> 5;           // 0..15
        #pragma unroll
        for (int p = 0; p < 4; ++p) {
            int c = p * 64 + cq * 4;
            float v0 = xb[(size_t)(c + 0) * NN + n];
            float v1 = xb[(size_t)(c + 1) * NN + n];
            float v2 = xb[(size_t)(c + 2) * NN + n];
            float v3 = xb[(size_t)(c + 3) * NN + n];
            ushort4v u4;
            u4[0] = f2bf(v0); u4[1] = f2bf(v1); u4[2] = f2bf(v2); u4[3] = f2bf(v3);
            int addr = ((4 * p + (cq >> 2)) * 64 + n + 32 * ((cq >> 1) & 1)) * 8
                       + 4 * (cq & 1);
            *(ushort4v*)&xf[addr] = u4;
        }
    }
    __syncthreads();

    floatx16 acc;
    #pragma unroll
    for (int i = 0; i < 16; ++i) acc[i] = 0.f;

    for (int kblk = 0; kblk < 16; ++kblk) {
        bf16x8 bf = *(const bf16x8*)&xf[kblk * 512 + l * 8];
        bf16x8 af = *(const bf16x8*)(What + ((size_t)(w * 16 + kblk) * 64 + l) * 8);
        acc = __builtin_amdgcn_mfma_f32_32x32x16_bf16(af, bf, acc, 0, 0, 0);
    }

    auto store_qk = [&](unsigned short* dst, const floatx16& a) {
        size_t base = (size_t)(b * 128 + nt) * 1024;
        #pragma unroll
        for (int sb = 0; sb < 2; ++sb) {
            ushort4v xp, yp;
            #pragma unroll
            for (int i = 0; i < 4; ++i) {
                xp[i] = f2bf(a[8 * sb + i]);
                yp[i] = f2bf(a[8 * sb + 4 + i]);
            }
            uint4v st = hmerge(xp, yp, h);
            *(uint4v*)(dst + base + (size_t)sb * 512 + (size_t)l * 8) = st;
        }
    };

    if (w == 0)      store_qk(qh, acc);
    else if (w == 1) store_qk(kh, acc);

    __syncthreads();   // all xf (GEMM B-frag) reads done; reuse xf for V

    if (w >= 2) {
        const int cblk = w - 2;
        const int chunk = cblk * 2 + (l31 >> 4);
        const int hib = (l31 >> 3) & 1;
        #pragma unroll
        for (int r = 0; r < 16; ++r) {
            int rowo = (r & 3) + 8 * (r >> 2) + 4 * h;
            int unit = chunk * 64 + hib * 32 + rowo;
            int pu = unit ^ ((unit >> 5) & 7);
            xf[pu * 8 + (l31 & 7)] = f2bf(acc[r]);
        }
    }

    __syncthreads();

    if (t < 512) {
        #pragma unroll
        for (int p = 0; p < 2; ++p) {
            int Lu = p * 512 + t;             // logical unit 0..1023
            int pu = Lu ^ ((Lu >> 5) & 7);
            uint4v d = *(const uint4v*)&xf[pu * 8];
            int chunk = Lu >> 6;
            int cblk = chunk >> 1, sub = chunk & 1;
            size_t dst = (((size_t)b * 8 + cblk) * 256 + nt * 2 + sub) * 512
                         + (size_t)(Lu & 63) * 8;
            *(uint4v*)(vh + dst) = d;
        }
    }
}

// ---------------------------------------------------------------------------
// K2: flash attention, Q-tile 64, 8 waves, key-split 2, PIPELINE-ROTATED.
// grid (64 qt-pairs, 2 ks, 4 b) = 512 blocks; XCD remap combo = lin&7.
// Fixed-shift softmax P = 2^(S-12). Body(it) = { S(it+1) MFMA; V(it) loads;
// softmax(it+1) + store -> buf[(it+1)&1]; K(it+2) loads; PV(it) from
// buf[it&1]; barrier }. One barrier/it; double-buffered p_lds.
// ---------------------------------------------------------------------------
#define SM_M0 12.0f

__global__ __launch_bounds__(512, 4) void attn_kernel(
    const unsigned short* __restrict__ qh, const unsigned short* __restrict__ kh,
    const unsigned short* __restrict__ vh, unsigned short* __restrict__ Opart,
    float* __restrict__ ml)
{
    __shared__ unsigned short p_lds[2 * 16 * 64 * 8];   // 32 KB, double-buffered
    __shared__ float psum_s[8][32];

    const int t = threadIdx.x;
    const int w = t >> 6;          // 0..7
    const int l = t & 63;
    const int l31 = l & 31;
    const int h = l >> 5;
    const int wk = w & 3;          // key sub-slice
    const int hq = w >> 2;         // q-half for S phase

    const int lin = blockIdx.x + ((int)blockIdx.y << 6) + ((int)blockIdx.z << 7);
    const int combo = lin & 7;
    const int gp = lin >> 3;                          // 0..63 qt-pair
    const int ks = combo & 1;
    const int b  = combo >> 1;
    const int g0 = 2 * gp, g1 = 2 * gp + 1;

    const unsigned short* qB = qh + (size_t)(b * 128 + (hq ? g1 : g0)) * 1024;
    const unsigned short* kB = kh + (size_t)b * 128 * 1024;
    const unsigned short* vB = vh + (size_t)b * 8 * 256 * 512;

    bf16x8 qf0 = *(const bf16x8*)(qB + l * 8);
    bf16x8 qf1 = *(const bf16x8*)(qB + 512 + l * 8);

    float l_loc = 0.f;
    floatx16 acc_a, acc_b;        // cblk w, q-halves a/b
    #pragma unroll
    for (int i = 0; i < 16; ++i) { acc_a[i] = 0.f; acc_b[i] = 0.f; }

    // softmax + pack + store helper: P(j) -> buffer (j&1)
    auto softmax_store = [&](const floatx16& sacc, int j) {
        const int pb = (j & 1) << 13;
        float pv[16];
        #pragma unroll
        for (int r = 0; r < 16; ++r) pv[r] = __builtin_exp2f(sacc[r] - SM_M0);
        float s0 = (pv[0] + pv[1]) + (pv[2] + pv[3]);
        float s1 = (pv[4] + pv[5]) + (pv[6] + pv[7]);
        float s2 = (pv[8] + pv[9]) + (pv[10] + pv[11]);
        float s3 = (pv[12] + pv[13]) + (pv[14] + pv[15]);
        l_loc += (s0 + s1) + (s2 + s3);
        #pragma unroll
        for (int rg = 0; rg < 4; ++rg) {
            ushort4v pk;
            #pragma unroll
            for (int i = 0; i < 4; ++i) pk[i] = f2bf(pv[rg * 4 + i]);
            int idx = pb
                    + ((hq * 8 + 2 * wk + (rg >> 1)) * 64
                       + l31 + 32 * (rg & 1)) * 8 + 4 * h;
            *(ushort4v*)&p_lds[idx] = pk;
        }
    };

    // ---- prologue: S(0) -> softmax(0) -> P(0) in buf0; prefetch K(1) ----
    bf16x8 kf0 = *(const bf16x8*)(kB + (size_t)(ks * 64 + wk) * 1024 + l * 8);
    bf16x8 kf1 = *(const bf16x8*)(kB + (size_t)(ks * 64 + wk) * 1024 + 512 + l * 8);
    {
        floatx16 sacc;
        #pragma unroll
        for (int i = 0; i < 16; ++i) sacc[i] = 0.f;
        sacc = __builtin_amdgcn_mfma_f32_32x32x16_bf16(kf0, qf0, sacc, 0, 0, 0);
        sacc = __builtin_amdgcn_mfma_f32_32x32x16_bf16(kf1, qf1, sacc, 0, 0, 0);
        softmax_store(sacc, 0);
    }
    {
        const unsigned short* kn = kB + (size_t)(ks * 64 + 4 + wk) * 1024;
        kf0 = *(const bf16x8*)(kn + l * 8);
        kf1 = *(const bf16x8*)(kn + 512 + l * 8);
    }
    __syncthreads();   // P(0) visible

    for (int it = 0; it < 16; ++it) {
        const int pcur = (it & 1) << 13;

        // ---- S(it+1): independent of p_lds; feeds softmax below ----
        floatx16 sacc;
        if (it < 15) {
            #pragma unroll
            for (int i = 0; i < 16; ++i) sacc[i] = 0.f;
            __builtin_amdgcn_s_setprio(1);
            sacc = __builtin_amdgcn_mfma_f32_32x32x16_bf16(kf0, qf0, sacc, 0, 0, 0);
            sacc = __builtin_amdgcn_mfma_f32_32x32x16_bf16(kf1, qf1, sacc, 0, 0, 0);
            __builtin_amdgcn_s_setprio(0);
        }

        // ---- V(it) loads (L2-resident; in flight under softmax VALU) ----
        const unsigned short* v0b = vB + ((size_t)w * 256 + (ks * 16 + it) * 8) * 512;
        bf16x8 va0 = *(const bf16x8*)(v0b + 0 * 512 + l * 8);
        bf16x8 va1 = *(const bf16x8*)(v0b + 1 * 512 + l * 8);
        bf16x8 va2 = *(const bf16x8*)(v0b + 2 * 512 + l * 8);
        bf16x8 va3 = *(const bf16x8*)(v0b + 3 * 512 + l * 8);
        bf16x8 va4 = *(const bf16x8*)(v0b + 4 * 512 + l * 8);
        bf16x8 va5 = *(const bf16x8*)(v0b + 5 * 512 + l * 8);
        bf16x8 va6 = *(const bf16x8*)(v0b + 6 * 512 + l * 8);
        bf16x8 va7 = *(const bf16x8*)(v0b + 7 * 512 + l * 8);

        // ---- softmax(it+1) -> buf[(it+1)&1]; K(it+2) prefetch ----
        if (it < 15) {
            softmax_store(sacc, it + 1);
            if (it < 14) {
                const unsigned short* kn = kB + (size_t)(ks * 64 + (it + 2) * 4 + wk) * 1024;
                kf0 = *(const bf16x8*)(kn + l * 8);
                kf1 = *(const bf16x8*)(kn + 512 + l * 8);
            }
        }

        // ---- PV(it) from buf[it&1] (stored last region, barrier'd) ----
        bf16x8 pa = *(const bf16x8*)&p_lds[pcur + l * 8];
        bf16x8 pb = *(const bf16x8*)&p_lds[pcur + 4096 + l * 8];
        #pragma unroll
        for (int s = 0; s < 8; ++s) {
            bf16x8 vcur = (s == 0) ? va0 : (s == 1) ? va1 : (s == 2) ? va2
                        : (s == 3) ? va3 : (s == 4) ? va4 : (s == 5) ? va5
                        : (s == 6) ? va6 : va7;
            bf16x8 pa_n, pb_n;
            if (s < 7) {
                pa_n = *(const bf16x8*)&p_lds[pcur + ((s + 1) * 64 + l) * 8];
                pb_n = *(const bf16x8*)&p_lds[pcur + 4096 + ((s + 1) * 64 + l) * 8];
            }
            __builtin_amdgcn_s_setprio(1);
            acc_a = __builtin_amdgcn_mfma_f32_32x32x16_bf16(vcur, pa, acc_a, 0, 0, 0);
            acc_b = __builtin_amdgcn_mfma_f32_32x32x16_bf16(vcur, pb, acc_b, 0, 0, 0);
            __builtin_amdgcn_s_setprio(0);
            pa = pa_n; pb = pb_n;
        }

        // barrier: (1) P(it+1) stores visible for next PV; (2) all waves'
        // reads of buf[it&1] done before body(it+1) overwrites it.
        __syncthreads();
    }

    // ---- cross-wave l reduction: waves 0-3 -> half a, 4-7 -> half b ----
    float lt = l_loc + __shfl_xor(l_loc, 32);
    if (h == 0) psum_s[w][l31] = lt;
    __syncthreads();

    if (w == 0 && h == 0) {
        float l_run = (psum_s[0][l31] + psum_s[1][l31])
                    + (psum_s[2][l31] + psum_s[3][l31]);
        ml[((size_t)(b * 128 + g0) * 2 + ks) * 32 + l31] = l_run;
    }
    if (w == 4 && h == 0) {
        float l_run = (psum_s[4][l31] + psum_s[5][l31])
                    + (psum_s[6][l31] + psum_s[7][l31]);
        ml[((size_t)(b * 128 + g1) * 2 + ks) * 32 + l31] = l_run;
    }

    // ---- epilogue: full-line b128 stores (sP = 2*cblk + sb; cblk = w) ----
    unsigned short* opa = Opart + ((size_t)((b * 128 + g0) * 2 + ks)) * 8192;
    unsigned short* opb = Opart + ((size_t)((b * 128 + g1) * 2 + ks)) * 8192;
    #pragma unroll
    for (int ct = 0; ct < 2; ++ct) {
        const floatx16& a = ct ? acc_b : acc_a;
        unsigned short* op = ct ? opb : opa;
        #pragma unroll
        for (int sb = 0; sb < 2; ++sb) {
            ushort4v xp, yp;
            #pragma unroll
            for (int i = 0; i < 4; ++i) {
                xp[i] = f2bf(a[8 * sb + i]);
                yp[i] = f2bf(a[8 * sb + 4 + i]);
            }
            uint4v st = hmerge(xp, yp, h);
            int sP = 2 * w + sb;
            *(uint4v*)(op + ((size_t)sP * 64 + l) * 8) = st;
        }
    }
}

// ---------------------------------------------------------------------------
// K3: Wo GEMM (R6 exact). m-split grid (128 qt, 2 mhalf, 4 b), 4 waves;
// wave owns m-tile mt = mhalf*4 + w with TWO exact MFMA chains (one per
// key-split partial), then (a0+a1) * 1/(l0+l1) post-GEMM + gamma*out + x.
// ---------------------------------------------------------------------------
__global__ __launch_bounds__(256, 4) void out_kernel(
    const unsigned short* __restrict__ Opart, const float* __restrict__ ml,
    const unsigned short* __restrict__ WobF, const float* __restrict__ x,
    const float* __restrict__ gamma, float* __restrict__ out)
{
    const int t = threadIdx.x;
    const int w = t >> 6;
    const int l = t & 63;
    const int l31 = l & 31;
    const int h = l >> 5;
    const int qt = blockIdx.x, mhalf = blockIdx.y, b = blockIdx.z;
    const int mt = mhalf * 4 + w;

    const size_t slot2 = (size_t)(b * 128 + qt) * 2;
    float l0 = ml[(slot2 + 0) * 32 + l31];
    float l1 = ml[(slot2 + 1) * 32 + l31];
    float rL = 1.0f / (l0 + l1);     // per-lane: D-layout col = l31 = query

    const unsigned short* o0 = Opart + (slot2 + 0) * 8192;
    const unsigned short* o1 = Opart + (slot2 + 1) * 8192;

    floatx16 a0, a1;
    #pragma unroll
    for (int i = 0; i < 16; ++i) { a0[i] = 0.f; a1[i] = 0.f; }

    for (int s = 0; s < 16; ++s) {
        bf16x8 f0 = *(const bf16x8*)(o0 + (s * 64 + l) * 8);
        bf16x8 f1 = *(const bf16x8*)(o1 + (s * 64 + l) * 8);
        bf16x8 af = *(const bf16x8*)(WobF + ((size_t)(mt * 16 + s) * 64 + l) * 8);
        a0 = __builtin_amdgcn_mfma_f32_32x32x16_bf16(af, f0, a0, 0, 0, 0);
        a1 = __builtin_amdgcn_mfma_f32_32x32x16_bf16(af, f1, a1, 0, 0, 0);
    }

    const float gm = gamma[0];
    #pragma unroll
    for (int r = 0; r < 16; ++r) {
        float v = (a0[r] + a1[r]) * rL;
        int o = mt * 32 + (r & 3) + 8 * (r >> 2) + 4 * h;
        int n = qt * 32 + l31;
        size_t oi = ((size_t)(b * 256 + o)) * NN + n;
        out[oi] = gm * v + x[oi];
    }
}

// ---------------------------------------------------------------------------
extern "C" void kernel_launch(void* const* d_in, const int* in_sizes, int n_in,
                              void* d_out, int out_size, void* d_ws, size_t ws_size,
                              hipStream_t stream)
{
    const float* x     = (const float*)d_in[0];
    const float* Wq    = (const float*)d_in[1];
    const float* Wk    = (const float*)d_in[2];
    const float* Wv    = (const float*)d_in[3];
    const float* Wo    = (const float*)d_in[4];
    const float* gamma = (const float*)d_in[5];
    float* out = (float*)d_out;

    char* wsb = (char*)d_ws;
    unsigned short* qh    = (unsigned short*)(wsb);                          // 1 MB
    unsigned short* kh    = (unsigned short*)(wsb + (1u << 20));             // 1 MB
    unsigned short* vh    = (unsigned short*)(wsb + (2u << 20));             // 8 MB
    unsigned short* What  = (unsigned short*)(wsb + (10u << 20));            // 160 KB
    unsigned short* WobF  = (unsigned short*)(wsb + (10u << 20) + (256u << 10)); // 128 KB
    unsigned short* Opart = (unsigned short*)(wsb + (11u << 20));            // 16.8 MB (ks=2)
    float*          ml    = (float*)         (wsb + (45u << 20));            // 128 KB

    wconv_kernel<<<320, 256, 0, stream>>>(Wq, Wk, Wv, Wo, What, WobF);

    dim3 g1(128, BATCH);
    qkv_kernel<<<g1, 640, 0, stream>>>(x, What, qh, kh, vh);

    dim3 g2(64, 2, BATCH);
    attn_kernel<<<g2, 512, 0, stream>>>(qh, kh, vh, Opart, ml);

    dim3 g3(128, 2, BATCH);
    out_kernel<<<g3, 256, 0, stream>>>(Opart, ml, WobF, x, gamma, out);
}